// Round 2
// baseline (417.656 us; speedup 1.0000x reference)
//
#include <hip/hip_runtime.h>

typedef __bf16 bf16_t;
typedef __bf16 bf16x8 __attribute__((ext_vector_type(8)));
typedef float f32x4 __attribute__((ext_vector_type(4)));

#define KN 50

// packed weight layout in d_ws (all bf16, [col][k] i.e. transposed):
// W1t: [64][96]  (k 72..95 zero-padded)
// W2t: [64][64]
// A1t: [64][128]
// A2t: [64][64]
#define W1T_ELEMS 6144
#define W2T_ELEMS 4096
#define A1T_ELEMS 8192
#define A2T_ELEMS 4096
#define TOTW (W1T_ELEMS + W2T_ELEMS + A1T_ELEMS + A2T_ELEMS)
#define W2T_OFF (W1T_ELEMS)
#define A1T_OFF (W1T_ELEMS + W2T_ELEMS)
#define A2T_OFF (W1T_ELEMS + W2T_ELEMS + A1T_ELEMS)

__global__ __launch_bounds__(256) void pack_weights_k(
    const float* __restrict__ w1, const float* __restrict__ w2,
    const float* __restrict__ a1, const float* __restrict__ a2,
    bf16_t* __restrict__ wp)
{
  int idx = blockIdx.x * 256 + threadIdx.x;
  if (idx >= TOTW) return;
  float v;
  if (idx < W1T_ELEMS) {
    int n = idx / 96, k = idx % 96;           // W1t[n][k] = w1[k][n], pad k>=72
    v = (k < 72) ? w1[k * 64 + n] : 0.f;
  } else if (idx < A1T_OFF) {
    int e = idx - W2T_OFF; int n = e >> 6, k = e & 63;
    v = w2[k * 64 + n];
  } else if (idx < A2T_OFF) {
    int e = idx - A1T_OFF; int n = e >> 7, k = e & 127;
    v = a1[k * 64 + n];
  } else {
    int e = idx - A2T_OFF; int n = e >> 6, k = e & 63;
    v = a2[k * 64 + n];
  }
  wp[idx] = (bf16_t)v;
}

__device__ __forceinline__ bf16x8 cvt8(float4 a, float4 b) {
  bf16x8 r;
  r[0] = (bf16_t)a.x; r[1] = (bf16_t)a.y; r[2] = (bf16_t)a.z; r[3] = (bf16_t)a.w;
  r[4] = (bf16_t)b.x; r[5] = (bf16_t)b.y; r[6] = (bf16_t)b.z; r[7] = (bf16_t)b.w;
  return r;
}

__global__ __launch_bounds__(256, 5) void social_agg_k(
    const int* __restrict__ nodes,
    const int* __restrict__ nidx,
    const int* __restrict__ nlen,
    const float* __restrict__ labels,
    const float* __restrict__ u2e,
    const float* __restrict__ b1v,
    const float* __restrict__ b2v,
    const float* __restrict__ ab1v,
    const float* __restrict__ ab2v,
    const float* __restrict__ a3w,
    const float* __restrict__ a3b,
    const bf16_t* __restrict__ wp,
    float* __restrict__ out)
{
  __shared__ __align__(16) bf16_t Hs[64][72];   // stage1 out / stage3 out (reused)
  __shared__ __align__(16) bf16_t Os[64][72];   // o_history bf16 (stage-3 operand)
  __shared__ float sco[64];
  __shared__ float part[4][64];

  const int b    = blockIdx.x;
  const int tid  = threadIdx.x;
  const int lane = tid & 63;
  const int w    = tid >> 6;
  const int m0   = w * 16;
  const int lrow = lane & 15;   // A-row / B-col / C-col
  const int lg   = lane >> 4;   // k-group / C row-group
  const int len  = nlen[b];
  const int node = nodes[b];

  // ---- stage-1 A fragments straight from global (no LDS X) ----
  const int row  = m0 + lrow;
  const int crow = (row < KN) ? row : (KN - 1);   // clamp: finite garbage, masked later
  const int gi   = nidx[b * KN + crow];
  const float* xr = u2e + (size_t)gi * 64;
  float4 x0 = *reinterpret_cast<const float4*>(xr + lg * 8);
  float4 x1 = *reinterpret_cast<const float4*>(xr + lg * 8 + 4);
  float4 x2 = *reinterpret_cast<const float4*>(xr + 32 + lg * 8);
  float4 x3 = *reinterpret_cast<const float4*>(xr + 32 + lg * 8 + 4);
  float4 l0 = {0.f, 0.f, 0.f, 0.f}, l1 = {0.f, 0.f, 0.f, 0.f};
  if (lg == 0) {   // cols 64..71 = labels; cols 72..95 stay zero (W1t rows are zero there too)
    const float* lb = labels + ((size_t)b * KN + crow) * 8;
    l0 = *reinterpret_cast<const float4*>(lb);
    l1 = *reinterpret_cast<const float4*>(lb + 4);
  }
  bf16x8 xa[3];
  xa[0] = cvt8(x0, x1);
  xa[1] = cvt8(x2, x3);
  xa[2] = cvt8(l0, l1);

  // u_rep fragments (row-broadcast within lg groups)
  const float* ur = u2e + (size_t)node * 64;
  float4 u0 = *reinterpret_cast<const float4*>(ur + lg * 8);
  float4 u1 = *reinterpret_cast<const float4*>(ur + lg * 8 + 4);
  float4 u2v = *reinterpret_cast<const float4*>(ur + 32 + lg * 8);
  float4 u3 = *reinterpret_cast<const float4*>(ur + 32 + lg * 8 + 4);
  bf16x8 ua0 = cvt8(u0, u1);
  bf16x8 ua1 = cvt8(u2v, u3);

  const bf16_t* W1t = wp;
  const bf16_t* W2t = wp + W2T_OFF;
  const bf16_t* A1t = wp + A1T_OFF;
  const bf16_t* A2t = wp + A2T_OFF;

  const f32x4 zero4 = {0.f, 0.f, 0.f, 0.f};
  f32x4 acc[4];

  // ================= stage 1: H = relu(X @ W1 + b1), K=96 =================
#pragma unroll
  for (int t = 0; t < 4; ++t) acc[t] = zero4;
#pragma unroll
  for (int s = 0; s < 3; ++s) {
#pragma unroll
    for (int t = 0; t < 4; ++t) {
      bf16x8 bf_ = *reinterpret_cast<const bf16x8*>(W1t + (t * 16 + lrow) * 96 + s * 32 + lg * 8);
      acc[t] = __builtin_amdgcn_mfma_f32_16x16x32_bf16(xa[s], bf_, acc[t], 0, 0, 0);
    }
  }
#pragma unroll
  for (int t = 0; t < 4; ++t) {
    const int col = t * 16 + lrow;
    const float bias = b1v[col];
#pragma unroll
    for (int r = 0; r < 4; ++r) {
      float v = acc[t][r] + bias;
      v = v > 0.f ? v : 0.f;
      Hs[m0 + lg * 4 + r][col] = (bf16_t)v;
    }
  }

  // ================= stage 2: O = relu(H @ W2 + b2), K=64 =================
#pragma unroll
  for (int t = 0; t < 4; ++t) acc[t] = zero4;
#pragma unroll
  for (int s = 0; s < 2; ++s) {
    bf16x8 af = *reinterpret_cast<const bf16x8*>(&Hs[m0 + lrow][s * 32 + lg * 8]);
#pragma unroll
    for (int t = 0; t < 4; ++t) {
      bf16x8 bf_ = *reinterpret_cast<const bf16x8*>(W2t + (t * 16 + lrow) * 64 + s * 32 + lg * 8);
      acc[t] = __builtin_amdgcn_mfma_f32_16x16x32_bf16(af, bf_, acc[t], 0, 0, 0);
    }
  }
  f32x4 osv[4];   // fp32 copy of O for the aggregate (register-resident)
#pragma unroll
  for (int t = 0; t < 4; ++t) {
    const int col = t * 16 + lrow;
    const float bias = b2v[col];
#pragma unroll
    for (int r = 0; r < 4; ++r) {
      float v = acc[t][r] + bias;
      v = v > 0.f ? v : 0.f;
      osv[t][r] = v;
      Os[m0 + lg * 4 + r][col] = (bf16_t)v;
    }
  }

  // ============ stage 3: A1 = relu([O | u_rep] @ a1W + a1b), K=128 ============
#pragma unroll
  for (int t = 0; t < 4; ++t) acc[t] = zero4;
#pragma unroll
  for (int s = 0; s < 4; ++s) {
    bf16x8 af;
    if (s < 2)      af = *reinterpret_cast<const bf16x8*>(&Os[m0 + lrow][s * 32 + lg * 8]);
    else if (s == 2) af = ua0;
    else             af = ua1;
#pragma unroll
    for (int t = 0; t < 4; ++t) {
      bf16x8 bf_ = *reinterpret_cast<const bf16x8*>(A1t + (t * 16 + lrow) * 128 + s * 32 + lg * 8);
      acc[t] = __builtin_amdgcn_mfma_f32_16x16x32_bf16(af, bf_, acc[t], 0, 0, 0);
    }
  }
#pragma unroll
  for (int t = 0; t < 4; ++t) {
    const int col = t * 16 + lrow;
    const float bias = ab1v[col];
#pragma unroll
    for (int r = 0; r < 4; ++r) {
      float v = acc[t][r] + bias;
      v = v > 0.f ? v : 0.f;
      Hs[m0 + lg * 4 + r][col] = (bf16_t)v;   // reuse Hs
    }
  }

  // ======= stage 4: A2 = relu(A1 @ a2W + a2b), K=64; scores = A2 @ a3 + b3 =======
#pragma unroll
  for (int t = 0; t < 4; ++t) acc[t] = zero4;
#pragma unroll
  for (int s = 0; s < 2; ++s) {
    bf16x8 af = *reinterpret_cast<const bf16x8*>(&Hs[m0 + lrow][s * 32 + lg * 8]);
#pragma unroll
    for (int t = 0; t < 4; ++t) {
      bf16x8 bf_ = *reinterpret_cast<const bf16x8*>(A2t + (t * 16 + lrow) * 64 + s * 32 + lg * 8);
      acc[t] = __builtin_amdgcn_mfma_f32_16x16x32_bf16(af, bf_, acc[t], 0, 0, 0);
    }
  }
  {
    float pr[4] = {0.f, 0.f, 0.f, 0.f};
#pragma unroll
    for (int t = 0; t < 4; ++t) {
      const int col = t * 16 + lrow;
      const float bias = ab2v[col];
      const float a3c  = a3w[col];
#pragma unroll
      for (int r = 0; r < 4; ++r) {
        float v = acc[t][r] + bias;
        v = v > 0.f ? v : 0.f;
        pr[r] += v * a3c;
      }
    }
#pragma unroll
    for (int r = 0; r < 4; ++r) {
#pragma unroll
      for (int m = 1; m < 16; m <<= 1) pr[r] += __shfl_xor(pr[r], m, 64);
    }
    if (lrow == 0) {
      const float a3bias = a3b[0];
#pragma unroll
      for (int r = 0; r < 4; ++r) sco[m0 + lg * 4 + r] = pr[r] + a3bias;
    }
  }
  __syncthreads();

  // ===== masked softmax, computed redundantly by every wave (no extra barrier) =====
  float att4[4];
  {
    const bool valid = lane < len;
    float s = valid ? sco[lane] : -1e30f;
    float m = s;
#pragma unroll
    for (int k = 1; k < 64; k <<= 1) m = fmaxf(m, __shfl_xor(m, k, 64));
    float e = valid ? __expf(s - m) : 0.f;
    float sm = e;
#pragma unroll
    for (int k = 1; k < 64; k <<= 1) sm += __shfl_xor(sm, k, 64);
    float att_own = (sm > 0.f) ? e / sm : 0.f;   // att for block-row `lane`
#pragma unroll
    for (int r = 0; r < 4; ++r) att4[r] = __shfl(att_own, m0 + lg * 4 + r, 64);
  }

  // ===== aggregate from register-resident fp32 O =====
  {
#pragma unroll
    for (int t = 0; t < 4; ++t) {
      float p = att4[0] * osv[t][0] + att4[1] * osv[t][1]
              + att4[2] * osv[t][2] + att4[3] * osv[t][3];
      p += __shfl_xor(p, 16, 64);
      p += __shfl_xor(p, 32, 64);
      if (lg == 0) part[w][t * 16 + lrow] = p;   // col-sum over this wave's 16 rows
    }
  }
  __syncthreads();
  if (tid < 64) {
    float v = part[0][tid] + part[1][tid] + part[2][tid] + part[3][tid];
    out[(size_t)b * 64 + tid] = (len > 0) ? v : u2e[(size_t)node * 64 + tid];
  }
}

extern "C" void kernel_launch(void* const* d_in, const int* in_sizes, int n_in,
                              void* d_out, int out_size, void* d_ws, size_t ws_size,
                              hipStream_t stream) {
  (void)in_sizes; (void)n_in; (void)out_size; (void)ws_size;
  const int*   nodes  = (const int*)d_in[0];
  const int*   nidx   = (const int*)d_in[1];
  const int*   nlen   = (const int*)d_in[2];
  const float* labels = (const float*)d_in[3];
  const float* u2e    = (const float*)d_in[4];
  const float* w1W    = (const float*)d_in[5];
  const float* w1b    = (const float*)d_in[6];
  const float* w2W    = (const float*)d_in[7];
  const float* w2b    = (const float*)d_in[8];
  const float* a1W    = (const float*)d_in[9];
  const float* a1b    = (const float*)d_in[10];
  const float* a2W    = (const float*)d_in[11];
  const float* a2b    = (const float*)d_in[12];
  const float* a3W    = (const float*)d_in[13];
  const float* a3b    = (const float*)d_in[14];
  float* out = (float*)d_out;
  bf16_t* wp = (bf16_t*)d_ws;

  pack_weights_k<<<(TOTW + 255) / 256, 256, 0, stream>>>(w1W, w2W, a1W, a2W, wp);
  social_agg_k<<<16384, 256, 0, stream>>>(nodes, nidx, nlen, labels, u2e,
                                          w1b, w2b, a1b, a2b, a3W, a3b, wp, out);
}

// Round 4
// 228.783 us; speedup vs baseline: 1.8256x; 1.8256x over previous
//
#include <hip/hip_runtime.h>

typedef __bf16 bf16_t;
typedef __bf16 bf16x8 __attribute__((ext_vector_type(8)));
typedef float f32x4 __attribute__((ext_vector_type(4)));

#define KN 50
#define B_TOT 16384
#define NITER 16
#define NBLK (B_TOT / NITER)

// padded weight layout in d_ws AND in LDS (bf16 elems), strides keep
// ds_read_b128 B-fragments at <=2-way bank aliasing (free):
// W1: [64][104] (k<72 data, rest 0)   off 0
// W2: [64][72]  (k<64 data)           off 6656
// A1: [64][136] (k<128 data)          off 11264
// A2: [64][72]  (k<64 data)           off 19968
#define W1_OFF 0
#define W1_STR 104
#define W2_OFF 6656
#define W2_STR 72
#define A1_OFF 11264
#define A1_STR 136
#define A2_OFF 19968
#define A2_STR 72
#define W_ELEMS 24576
#define BIAS_BYTE_OFF (W_ELEMS * 2)
#define PACK_TOT (W_ELEMS + 321)

__global__ __launch_bounds__(256) void pack_weights_k(
    const float* __restrict__ w1, const float* __restrict__ w2,
    const float* __restrict__ a1, const float* __restrict__ a2,
    const float* __restrict__ b1, const float* __restrict__ b2,
    const float* __restrict__ ab1, const float* __restrict__ ab2,
    const float* __restrict__ a3w, const float* __restrict__ a3b,
    void* __restrict__ ws)
{
  int idx = blockIdx.x * 256 + threadIdx.x;
  if (idx >= PACK_TOT) return;
  bf16_t* wp = (bf16_t*)ws;
  float* bp = (float*)((char*)ws + BIAS_BYTE_OFF);
  if (idx < W2_OFF) {
    int n = idx / W1_STR, k = idx % W1_STR;
    wp[idx] = (bf16_t)((k < 72) ? w1[k * 64 + n] : 0.f);
  } else if (idx < A1_OFF) {
    int e = idx - W2_OFF; int n = e / W2_STR, k = e % W2_STR;
    wp[idx] = (bf16_t)((k < 64) ? w2[k * 64 + n] : 0.f);
  } else if (idx < A2_OFF) {
    int e = idx - A1_OFF; int n = e / A1_STR, k = e % A1_STR;
    wp[idx] = (bf16_t)((k < 128) ? a1[k * 64 + n] : 0.f);
  } else if (idx < W_ELEMS) {
    int e = idx - A2_OFF; int n = e / A2_STR, k = e % A2_STR;
    wp[idx] = (bf16_t)((k < 64) ? a2[k * 64 + n] : 0.f);
  } else {
    int e = idx - W_ELEMS;
    float v;
    if (e < 64) v = b1[e];
    else if (e < 128) v = b2[e - 64];
    else if (e < 192) v = ab1[e - 128];
    else if (e < 256) v = ab2[e - 192];
    else if (e < 320) v = a3w[e - 256];
    else v = a3b[0];
    bp[e] = v;
  }
}

__device__ __forceinline__ bf16x8 cvt8(float4 a, float4 b) {
  bf16x8 r;
  r[0] = (bf16_t)a.x; r[1] = (bf16_t)a.y; r[2] = (bf16_t)a.z; r[3] = (bf16_t)a.w;
  r[4] = (bf16_t)b.x; r[5] = (bf16_t)b.y; r[6] = (bf16_t)b.z; r[7] = (bf16_t)b.w;
  return r;
}

__device__ __forceinline__ float4 ldf4(const float* p) {
  return *reinterpret_cast<const float4*>(p);
}

__global__ __launch_bounds__(256, 2) void social_agg_k(
    const int* __restrict__ nodes,
    const int* __restrict__ nidx,
    const int* __restrict__ nlen,
    const float* __restrict__ labels,
    const float* __restrict__ u2e,
    const void* __restrict__ wsv,
    float* __restrict__ out)
{
  __shared__ __align__(16) bf16_t WL[W_ELEMS];   // 48 KB packed weights
  __shared__ __align__(16) bf16_t Hs[64][72];
  __shared__ __align__(16) bf16_t Os[64][72];
  __shared__ float sco[64];
  __shared__ float part[4][64];

  const bf16_t* wp = (const bf16_t*)wsv;
  const float*  bp = (const float*)((const char*)wsv + BIAS_BYTE_OFF);

  const int tid  = threadIdx.x;
  const int lane = tid & 63;
  const int w    = tid >> 6;
  const int m0   = w * 16;
  const int lrow = lane & 15;
  const int lg   = lane >> 4;

  // ---- stage all weights into LDS (contiguous b128 copy) ----
  {
    const bf16x8* src = (const bf16x8*)wp;
    bf16x8* dst = (bf16x8*)WL;
#pragma unroll
    for (int c = 0; c < W_ELEMS / 8 / 256; ++c)   // 12 iters
      dst[c * 256 + tid] = src[c * 256 + tid];
  }

  // ---- per-thread bias/a3 registers (col fixed per thread) ----
  float bb1[4], bb2[4], ba1[4], ba2[4], a3c[4];
#pragma unroll
  for (int t = 0; t < 4; ++t) {
    const int col = t * 16 + lrow;
    bb1[t] = bp[col];       bb2[t] = bp[64 + col];
    ba1[t] = bp[128 + col]; ba2[t] = bp[192 + col];
    a3c[t] = bp[256 + col];
  }
  const float a3bias = bp[320];

  const int row  = m0 + lrow;
  const int crow = (row < KN) ? row : (KN - 1);
  const int b0   = blockIdx.x * NITER;

  // ---- prologue prefetch: indices + data for it=0, indices for it=1 ----
  int giC = nidx[(size_t)b0 * KN + crow];
  int ndC = nodes[b0];
  int lnC = nlen[b0];
  const float* xr = u2e + (size_t)giC * 64;
  float4 px0 = ldf4(xr + lg * 8);
  float4 px1 = ldf4(xr + lg * 8 + 4);
  float4 px2 = ldf4(xr + 32 + lg * 8);
  float4 px3 = ldf4(xr + 32 + lg * 8 + 4);
  float4 pl0 = {0.f, 0.f, 0.f, 0.f}, pl1 = {0.f, 0.f, 0.f, 0.f};
  if (lg == 0) {
    const float* lb = labels + ((size_t)b0 * KN + crow) * 8;
    pl0 = ldf4(lb); pl1 = ldf4(lb + 4);
  }
  const float* ur = u2e + (size_t)ndC * 64;
  float4 pu0 = ldf4(ur + lg * 8);
  float4 pu1 = ldf4(ur + lg * 8 + 4);
  float4 pu2 = ldf4(ur + 32 + lg * 8);
  float4 pu3 = ldf4(ur + 32 + lg * 8 + 4);
  int giN = nidx[(size_t)(b0 + 1) * KN + crow];
  int ndN = nodes[b0 + 1];
  int lnN = nlen[b0 + 1];

  __syncthreads();   // WL ready

  const f32x4 zero4 = {0.f, 0.f, 0.f, 0.f};

  for (int it = 0; it < NITER; ++it) {
    const int b = b0 + it;

    // convert current node's prefetched data (waits on last iter's loads)
    bf16x8 xa0 = cvt8(px0, px1);
    bf16x8 xa1 = cvt8(px2, px3);
    bf16x8 xa2 = cvt8(pl0, pl1);
    bf16x8 ua0 = cvt8(pu0, pu1);
    bf16x8 ua1 = cvt8(pu2, pu3);
    const int lenCur = lnC;
    const int ndCur  = ndC;

    // issue next node's data loads (indices already in flight from last iter)
    if (it + 1 < NITER) {
      const float* xr2 = u2e + (size_t)giN * 64;
      px0 = ldf4(xr2 + lg * 8);
      px1 = ldf4(xr2 + lg * 8 + 4);
      px2 = ldf4(xr2 + 32 + lg * 8);
      px3 = ldf4(xr2 + 32 + lg * 8 + 4);
      if (lg == 0) {
        const float* lb2 = labels + ((size_t)(b + 1) * KN + crow) * 8;
        pl0 = ldf4(lb2); pl1 = ldf4(lb2 + 4);
      }
      const float* ur2 = u2e + (size_t)ndN * 64;
      pu0 = ldf4(ur2 + lg * 8);
      pu1 = ldf4(ur2 + lg * 8 + 4);
      pu2 = ldf4(ur2 + 32 + lg * 8);
      pu3 = ldf4(ur2 + 32 + lg * 8 + 4);
      lnC = lnN; ndC = ndN;
      const int b2 = (it + 2 < NITER) ? (b + 2) : b;   // clamp; unused if past end
      giN = nidx[(size_t)b2 * KN + crow];
      ndN = nodes[b2];
      lnN = nlen[b2];
    }

    f32x4 acc[4];

    // ========== stage 1: H = relu(X @ W1 + b1), K=96 ==========
#pragma unroll
    for (int t = 0; t < 4; ++t) acc[t] = zero4;
#pragma unroll
    for (int s = 0; s < 3; ++s) {
      bf16x8 af = (s == 0) ? xa0 : (s == 1) ? xa1 : xa2;
#pragma unroll
      for (int t = 0; t < 4; ++t) {
        bf16x8 bf_ = *reinterpret_cast<const bf16x8*>(
            &WL[W1_OFF + (t * 16 + lrow) * W1_STR + s * 32 + lg * 8]);
        acc[t] = __builtin_amdgcn_mfma_f32_16x16x32_bf16(af, bf_, acc[t], 0, 0, 0);
      }
    }
#pragma unroll
    for (int t = 0; t < 4; ++t) {
      const int col = t * 16 + lrow;
#pragma unroll
      for (int r = 0; r < 4; ++r) {
        float v = acc[t][r] + bb1[t];
        v = v > 0.f ? v : 0.f;
        Hs[m0 + lg * 4 + r][col] = (bf16_t)v;
      }
    }

    // ========== stage 2: O = relu(H @ W2 + b2), K=64 ==========
#pragma unroll
    for (int t = 0; t < 4; ++t) acc[t] = zero4;
#pragma unroll
    for (int s = 0; s < 2; ++s) {
      bf16x8 af = *reinterpret_cast<const bf16x8*>(&Hs[m0 + lrow][s * 32 + lg * 8]);
#pragma unroll
      for (int t = 0; t < 4; ++t) {
        bf16x8 bf_ = *reinterpret_cast<const bf16x8*>(
            &WL[W2_OFF + (t * 16 + lrow) * W2_STR + s * 32 + lg * 8]);
        acc[t] = __builtin_amdgcn_mfma_f32_16x16x32_bf16(af, bf_, acc[t], 0, 0, 0);
      }
    }
    f32x4 osv[4];   // fp32 O copy for the aggregate
#pragma unroll
    for (int t = 0; t < 4; ++t) {
      const int col = t * 16 + lrow;
#pragma unroll
      for (int r = 0; r < 4; ++r) {
        float v = acc[t][r] + bb2[t];
        v = v > 0.f ? v : 0.f;
        osv[t][r] = v;
        Os[m0 + lg * 4 + r][col] = (bf16_t)v;
      }
    }

    // ========== stage 3: A1 = relu([O | u_rep] @ a1W + a1b), K=128 ==========
#pragma unroll
    for (int t = 0; t < 4; ++t) acc[t] = zero4;
#pragma unroll
    for (int s = 0; s < 4; ++s) {
      bf16x8 af;
      if (s < 2)       af = *reinterpret_cast<const bf16x8*>(&Os[m0 + lrow][s * 32 + lg * 8]);
      else if (s == 2) af = ua0;
      else             af = ua1;
#pragma unroll
      for (int t = 0; t < 4; ++t) {
        bf16x8 bf_ = *reinterpret_cast<const bf16x8*>(
            &WL[A1_OFF + (t * 16 + lrow) * A1_STR + s * 32 + lg * 8]);
        acc[t] = __builtin_amdgcn_mfma_f32_16x16x32_bf16(af, bf_, acc[t], 0, 0, 0);
      }
    }
#pragma unroll
    for (int t = 0; t < 4; ++t) {
      const int col = t * 16 + lrow;
#pragma unroll
      for (int r = 0; r < 4; ++r) {
        float v = acc[t][r] + ba1[t];
        v = v > 0.f ? v : 0.f;
        Hs[m0 + lg * 4 + r][col] = (bf16_t)v;   // reuse Hs
      }
    }

    // ===== stage 4: A2 = relu(A1 @ a2W + a2b), K=64; scores = A2 @ a3 + b3 =====
#pragma unroll
    for (int t = 0; t < 4; ++t) acc[t] = zero4;
#pragma unroll
    for (int s = 0; s < 2; ++s) {
      bf16x8 af = *reinterpret_cast<const bf16x8*>(&Hs[m0 + lrow][s * 32 + lg * 8]);
#pragma unroll
      for (int t = 0; t < 4; ++t) {
        bf16x8 bf_ = *reinterpret_cast<const bf16x8*>(
            &WL[A2_OFF + (t * 16 + lrow) * A2_STR + s * 32 + lg * 8]);
        acc[t] = __builtin_amdgcn_mfma_f32_16x16x32_bf16(af, bf_, acc[t], 0, 0, 0);
      }
    }
    {
      float pr[4] = {0.f, 0.f, 0.f, 0.f};
#pragma unroll
      for (int t = 0; t < 4; ++t) {
#pragma unroll
        for (int r = 0; r < 4; ++r) {
          float v = acc[t][r] + ba2[t];
          v = v > 0.f ? v : 0.f;
          pr[r] += v * a3c[t];
        }
      }
#pragma unroll
      for (int r = 0; r < 4; ++r) {
#pragma unroll
        for (int m = 1; m < 16; m <<= 1) pr[r] += __shfl_xor(pr[r], m, 64);
      }
      if (lrow == 0) {
#pragma unroll
        for (int r = 0; r < 4; ++r) sco[m0 + lg * 4 + r] = pr[r] + a3bias;
      }
    }
    __syncthreads();

    // ===== masked softmax, redundantly per wave =====
    float att4[4];
    {
      const bool valid = lane < lenCur;
      float s = valid ? sco[lane] : -1e30f;
      float m = s;
#pragma unroll
      for (int k = 1; k < 64; k <<= 1) m = fmaxf(m, __shfl_xor(m, k, 64));
      float e = valid ? __expf(s - m) : 0.f;
      float sm = e;
#pragma unroll
      for (int k = 1; k < 64; k <<= 1) sm += __shfl_xor(sm, k, 64);
      float att_own = (sm > 0.f) ? e / sm : 0.f;
#pragma unroll
      for (int r = 0; r < 4; ++r) att4[r] = __shfl(att_own, m0 + lg * 4 + r, 64);
    }

    // ===== aggregate from register-resident fp32 O =====
#pragma unroll
    for (int t = 0; t < 4; ++t) {
      float p = att4[0] * osv[t][0] + att4[1] * osv[t][1]
              + att4[2] * osv[t][2] + att4[3] * osv[t][3];
      p += __shfl_xor(p, 16, 64);
      p += __shfl_xor(p, 32, 64);
      if (lg == 0) part[w][t * 16 + lrow] = p;
    }
    __syncthreads();
    if (tid < 64) {
      float v = part[0][tid] + part[1][tid] + part[2][tid] + part[3][tid];
      if (lenCur > 0) out[(size_t)b * 64 + tid] = v;
      else            out[(size_t)b * 64 + tid] = u2e[(size_t)ndCur * 64 + tid];
    }
  }
}

extern "C" void kernel_launch(void* const* d_in, const int* in_sizes, int n_in,
                              void* d_out, int out_size, void* d_ws, size_t ws_size,
                              hipStream_t stream) {
  (void)in_sizes; (void)n_in; (void)out_size; (void)ws_size;
  const int*   nodes  = (const int*)d_in[0];
  const int*   nidx   = (const int*)d_in[1];
  const int*   nlen   = (const int*)d_in[2];
  const float* labels = (const float*)d_in[3];
  const float* u2e    = (const float*)d_in[4];
  const float* w1W    = (const float*)d_in[5];
  const float* w1b    = (const float*)d_in[6];
  const float* w2W    = (const float*)d_in[7];
  const float* w2b    = (const float*)d_in[8];
  const float* a1W    = (const float*)d_in[9];
  const float* a1b    = (const float*)d_in[10];
  const float* a2W    = (const float*)d_in[11];
  const float* a2b    = (const float*)d_in[12];
  const float* a3W    = (const float*)d_in[13];
  const float* a3b    = (const float*)d_in[14];
  float* out = (float*)d_out;

  pack_weights_k<<<(PACK_TOT + 255) / 256, 256, 0, stream>>>(
      w1W, w2W, a1W, a2W, w1b, w2b, a1b, a2b, a3W, a3b, d_ws);
  social_agg_k<<<NBLK, 256, 0, stream>>>(nodes, nidx, nlen, labels, u2e, d_ws, out);
}